// Round 1
// baseline (2816.248 us; speedup 1.0000x reference)
//
#include <hip/hip_runtime.h>
#include <hip/hip_bf16.h>
#include <cstdint>
#include <cstddef>

// SlabAttention on MI355X (gfx950).
// Stage 1: qkv = x @ qkv_w^T  (bf16 MFMA 16x16x32, 128x128 tiles)
//          epilogue: q=relu(q); k=relu(k+pos); scatter to (BH,N,32) bf16
// Stage 2: kv[bh] = k^T v (32x32), ksum[bh] = sum_j k  (vector fp32 + atomics)
// Stage 3: out_pre = (q@kv)*z + dwconv5x5(v) + b,  z = 1/(q.ksum+eps) -> (B,N,C) bf16
// Stage 4: out = out_pre @ proj_w^T + proj_b  (bf16 MFMA, fp32 out)
// Workspace use ~146 MB.

typedef __bf16 bf16;
typedef __attribute__((ext_vector_type(8))) __bf16 bf16x8;
typedef __attribute__((ext_vector_type(4))) __bf16 bf16x4;
typedef __attribute__((ext_vector_type(4))) float f32x4;

#define NHEADS 12
#define HD 32
#define BATCH 16
#define SEQ 4096
#define CDIM 384
#define BHN (BATCH*NHEADS)   // 192

// ---------------------------------------------------------------- K0: convert
__global__ void convert_w(const float* __restrict__ qkvw, const float* __restrict__ projw,
                          bf16* __restrict__ qkvw_b, bf16* __restrict__ projw_b,
                          float* __restrict__ kvz, float* __restrict__ ksz) {
    int i = blockIdx.x * 256 + threadIdx.x;
    int stride = gridDim.x * 256;
    const int nq = 3 * CDIM * CDIM;      // 442368
    const int np = CDIM * CDIM;          // 147456
    for (int idx = i; idx < nq; idx += stride) qkvw_b[idx] = (bf16)qkvw[idx];
    for (int idx = i; idx < np; idx += stride) projw_b[idx] = (bf16)projw[idx];
    for (int idx = i; idx < BHN * HD * HD; idx += stride) kvz[idx] = 0.f;
    for (int idx = i; idx < BHN * HD; idx += stride) ksz[idx] = 0.f;
}

// ---------------------------------------------------------------- K1: qkv GEMM
// A = x fp32 (65536 x 384), B = qkv_w bf16 (1152 x 384) both K-contiguous.
__global__ __launch_bounds__(256, 2)
void gemm_qkv(const float* __restrict__ X, const bf16* __restrict__ Wb,
              const float* __restrict__ pos,
              bf16* __restrict__ qh, bf16* __restrict__ kh, bf16* __restrict__ vh) {
    __shared__ bf16 As[128 * 64];
    __shared__ bf16 Bs[128 * 64];
    const int tid  = threadIdx.x;
    const int lane = tid & 63;
    const int wid  = tid >> 6;
    const int m0   = blockIdx.y * 128;
    const int n0   = blockIdx.x * 128;
    const int wm   = (wid & 1) * 64;
    const int wn   = (wid >> 1) * 64;
    const int lr   = lane & 15;   // fragment row/col
    const int lq   = lane >> 4;   // quad

    f32x4 acc[4][4] = {};

    for (int k0 = 0; k0 < CDIM; k0 += 64) {
        // stage A (fp32 -> bf16) and B (bf16), xor-swizzled 16B chunks
        #pragma unroll
        for (int it = 0; it < 4; ++it) {
            int cid = tid + it * 256;       // 1024 chunks of 8 elems
            int r = cid >> 3, c = cid & 7;
            const float* srcA = X + (size_t)(m0 + r) * CDIM + k0 + c * 8;
            float4 f0 = *(const float4*)srcA;
            float4 f1 = *(const float4*)(srcA + 4);
            bf16x8 ha;
            ha[0]=(bf16)f0.x; ha[1]=(bf16)f0.y; ha[2]=(bf16)f0.z; ha[3]=(bf16)f0.w;
            ha[4]=(bf16)f1.x; ha[5]=(bf16)f1.y; ha[6]=(bf16)f1.z; ha[7]=(bf16)f1.w;
            *(bf16x8*)&As[r * 64 + ((c ^ (r & 7))) * 8] = ha;
            *(bf16x8*)&Bs[r * 64 + ((c ^ (r & 7))) * 8] =
                *(const bf16x8*)&Wb[(size_t)(n0 + r) * CDIM + k0 + c * 8];
        }
        __syncthreads();
        #pragma unroll
        for (int ks = 0; ks < 2; ++ks) {
            bf16x8 af[4], bfr[4];
            #pragma unroll
            for (int mi = 0; mi < 4; ++mi) {
                int r = wm + mi * 16 + lr;
                af[mi] = *(const bf16x8*)&As[r * 64 + ((ks * 4 + lq) ^ (r & 7)) * 8];
            }
            #pragma unroll
            for (int ni = 0; ni < 4; ++ni) {
                int r = wn + ni * 16 + lr;
                bfr[ni] = *(const bf16x8*)&Bs[r * 64 + ((ks * 4 + lq) ^ (r & 7)) * 8];
            }
            #pragma unroll
            for (int mi = 0; mi < 4; ++mi)
                #pragma unroll
                for (int ni = 0; ni < 4; ++ni)
                    acc[mi][ni] = __builtin_amdgcn_mfma_f32_16x16x32_bf16(
                        af[mi], bfr[ni], acc[mi][ni], 0, 0, 0);
        }
        __syncthreads();
    }

    // epilogue: section is uniform per block (384 = 3*128)
    const int sec = n0 / CDIM;   // 0=q 1=k 2=v
    #pragma unroll
    for (int mi = 0; mi < 4; ++mi) {
        #pragma unroll
        for (int ni = 0; ni < 4; ++ni) {
            int n = n0 + wn + ni * 16 + lr;
            int c = n - sec * CDIM;
            int hh = c >> 5, d = c & 31;
            #pragma unroll
            for (int r = 0; r < 4; ++r) {
                int m = m0 + wm + mi * 16 + lq * 4 + r;
                int b = m >> 12, i = m & 4095;
                float v = acc[mi][ni][r];
                size_t dst = ((size_t)(b * NHEADS + hh) * SEQ + i) * HD + d;
                if (sec == 0) {
                    qh[dst] = (bf16)fmaxf(v, 0.f);
                } else if (sec == 1) {
                    v += pos[(size_t)i * CDIM + c];
                    kh[dst] = (bf16)fmaxf(v, 0.f);
                } else {
                    vh[dst] = (bf16)v;
                }
            }
        }
    }
}

// ---------------------------------------------------------------- K2: kv + ksum
__global__ __launch_bounds__(256, 2)
void kv_reduce(const bf16* __restrict__ kh, const bf16* __restrict__ vh,
               float* __restrict__ kv, float* __restrict__ ksum) {
    __shared__ bf16 kl[128 * 32];
    __shared__ bf16 vl[128 * 32];
    __shared__ float red[4 * 1024];
    const int tid = threadIdx.x;
    const int bh  = blockIdx.y;
    const int j0  = blockIdx.x * 512;
    const int w   = tid >> 6;
    const int c0  = ((tid >> 3) & 7) * 4;
    const int dg  = tid & 7;
    const int d0  = dg * 4;
    const bf16* kbase = kh + (size_t)bh * SEQ * HD;
    const bf16* vbase = vh + (size_t)bh * SEQ * HD;

    float acc[4][4] = {};
    float ksacc[4] = {};

    for (int sc = 0; sc < 4; ++sc) {
        int row0 = j0 + sc * 128;
        #pragma unroll
        for (int it = 0; it < 2; ++it) {
            int cid = tid + it * 256;      // 512 chunks
            int r = cid >> 2, q = cid & 3;
            *(bf16x8*)&kl[r * 32 + q * 8] = *(const bf16x8*)&kbase[(size_t)(row0 + r) * HD + q * 8];
            *(bf16x8*)&vl[r * 32 + q * 8] = *(const bf16x8*)&vbase[(size_t)(row0 + r) * HD + q * 8];
        }
        __syncthreads();
        const int jbeg = w * 32;
        for (int j = jbeg; j < jbeg + 32; ++j) {
            bf16x4 kq = *(const bf16x4*)&kl[j * 32 + c0];
            bf16x4 vq = *(const bf16x4*)&vl[j * 32 + d0];
            float kf[4], vf[4];
            #pragma unroll
            for (int a = 0; a < 4; ++a) { kf[a] = (float)kq[a]; vf[a] = (float)vq[a]; }
            #pragma unroll
            for (int a = 0; a < 4; ++a)
                #pragma unroll
                for (int bb = 0; bb < 4; ++bb) acc[a][bb] += kf[a] * vf[bb];
            if (dg == 0) {
                #pragma unroll
                for (int a = 0; a < 4; ++a) ksacc[a] += kf[a];
            }
        }
        __syncthreads();
    }
    // cross-wave reduce in LDS, then one atomic per element
    #pragma unroll
    for (int a = 0; a < 4; ++a)
        #pragma unroll
        for (int bb = 0; bb < 4; ++bb)
            red[w * 1024 + (c0 + a) * 32 + d0 + bb] = acc[a][bb];
    __syncthreads();
    {
        int e = tid * 4;
        f32x4 s = *(f32x4*)&red[e];
        s += *(f32x4*)&red[1024 + e];
        s += *(f32x4*)&red[2048 + e];
        s += *(f32x4*)&red[3072 + e];
        #pragma unroll
        for (int r = 0; r < 4; ++r) atomicAdd(&kv[(size_t)bh * 1024 + e + r], s[r]);
    }
    if (dg == 0) {
        #pragma unroll
        for (int a = 0; a < 4; ++a) atomicAdd(&ksum[bh * HD + c0 + a], ksacc[a]);
    }
}

// ---------------------------------------------------------------- K3: out_pre
__global__ __launch_bounds__(256, 2)
void attn_out(const bf16* __restrict__ qh, const bf16* __restrict__ vh,
              const float* __restrict__ kv, const float* __restrict__ ksum,
              const float* __restrict__ dwcw, const float* __restrict__ dwcb,
              bf16* __restrict__ outp) {
    __shared__ bf16 vt[12 * 64 * 32];   // 48 KB halo tile
    __shared__ float kvl[1024];
    __shared__ float ksl[32];
    __shared__ float wl[25 * 32];
    __shared__ float bl[32];
    const int tid = threadIdx.x;
    const int bh  = blockIdx.y;
    const int ys  = blockIdx.x * 8;     // strip of 8 spatial rows
    const bf16* vbase = vh + (size_t)bh * SEQ * HD;

    #pragma unroll
    for (int it = 0; it < 12; ++it) {
        int cid = tid + it * 256;        // 3072 chunks of 8 bf16
        int vy = cid >> 8;
        int xx = (cid >> 2) & 63;
        int q  = cid & 3;
        int gy = ys + vy - 2;
        bf16x8 val = {};
        if (gy >= 0 && gy < 64)
            val = *(const bf16x8*)&vbase[((size_t)gy * 64 + xx) * HD + q * 8];
        *(bf16x8*)&vt[(vy * 64 + xx) * HD + q * 8] = val;
    }
    {
        f32x4 t = *(const f32x4*)&kv[(size_t)bh * 1024 + tid * 4];
        *(f32x4*)&kvl[tid * 4] = t;
    }
    if (tid < 32) {
        ksl[tid] = ksum[bh * HD + tid];
        #pragma unroll
        for (int tap = 0; tap < 25; ++tap) wl[tap * 32 + tid] = dwcw[tid * 25 + tap];
        bl[tid] = dwcb[tid];
    }
    __syncthreads();

    const int dq = tid & 7, d0 = dq * 4;
    const int ri = tid >> 3;            // 0..31
    const int b = bh / NHEADS, hh = bh % NHEADS;
    const bf16* qbase = qh + (size_t)bh * SEQ * HD;

    for (int it = 0; it < 16; ++it) {
        int pix = ri + it * 32;          // 0..511
        int yy = pix >> 6;               // 0..7 within strip
        int x  = pix & 63;
        int tok = (ys + yy) * 64 + x;
        float zden = 1e-6f;
        float dot0 = 0, dot1 = 0, dot2 = 0, dot3 = 0;
        #pragma unroll
        for (int c4 = 0; c4 < 32; c4 += 4) {
            bf16x4 qv = *(const bf16x4*)&qbase[(size_t)tok * HD + c4];
            #pragma unroll
            for (int u = 0; u < 4; ++u) {
                float qf = (float)qv[u];
                int c = c4 + u;
                zden += qf * ksl[c];
                dot0 += qf * kvl[c * 32 + d0];
                dot1 += qf * kvl[c * 32 + d0 + 1];
                dot2 += qf * kvl[c * 32 + d0 + 2];
                dot3 += qf * kvl[c * 32 + d0 + 3];
            }
        }
        float z = 1.f / zden;
        float f0 = bl[d0], f1 = bl[d0 + 1], f2 = bl[d0 + 2], f3 = bl[d0 + 3];
        int vyc = yy + 2;
        #pragma unroll
        for (int dy = -2; dy <= 2; ++dy) {
            #pragma unroll
            for (int dx = -2; dx <= 2; ++dx) {
                int xx = x + dx;
                if (xx < 0 || xx >= 64) continue;
                int tap = (dy + 2) * 5 + (dx + 2);
                bf16x4 vv = *(const bf16x4*)&vt[((vyc + dy) * 64 + xx) * HD + d0];
                const float* wp = &wl[tap * 32 + d0];
                f0 += (float)vv[0] * wp[0];
                f1 += (float)vv[1] * wp[1];
                f2 += (float)vv[2] * wp[2];
                f3 += (float)vv[3] * wp[3];
            }
        }
        bf16x4 ov;
        ov[0] = (bf16)(dot0 * z + f0);
        ov[1] = (bf16)(dot1 * z + f1);
        ov[2] = (bf16)(dot2 * z + f2);
        ov[3] = (bf16)(dot3 * z + f3);
        *(bf16x4*)&outp[((size_t)b * SEQ + tok) * CDIM + hh * HD + d0] = ov;
    }
}

// ---------------------------------------------------------------- K4: proj GEMM
__global__ __launch_bounds__(256, 2)
void gemm_proj(const bf16* __restrict__ A, const bf16* __restrict__ Wb,
               const float* __restrict__ bias, float* __restrict__ out) {
    __shared__ bf16 As[128 * 64];
    __shared__ bf16 Bs[128 * 64];
    const int tid  = threadIdx.x;
    const int lane = tid & 63;
    const int wid  = tid >> 6;
    const int m0   = blockIdx.y * 128;
    const int n0   = blockIdx.x * 128;
    const int wm   = (wid & 1) * 64;
    const int wn   = (wid >> 1) * 64;
    const int lr   = lane & 15;
    const int lq   = lane >> 4;

    f32x4 acc[4][4] = {};

    for (int k0 = 0; k0 < CDIM; k0 += 64) {
        #pragma unroll
        for (int it = 0; it < 4; ++it) {
            int cid = tid + it * 256;
            int r = cid >> 3, c = cid & 7;
            *(bf16x8*)&As[r * 64 + ((c ^ (r & 7))) * 8] =
                *(const bf16x8*)&A[(size_t)(m0 + r) * CDIM + k0 + c * 8];
            *(bf16x8*)&Bs[r * 64 + ((c ^ (r & 7))) * 8] =
                *(const bf16x8*)&Wb[(size_t)(n0 + r) * CDIM + k0 + c * 8];
        }
        __syncthreads();
        #pragma unroll
        for (int ks = 0; ks < 2; ++ks) {
            bf16x8 af[4], bfr[4];
            #pragma unroll
            for (int mi = 0; mi < 4; ++mi) {
                int r = wm + mi * 16 + lr;
                af[mi] = *(const bf16x8*)&As[r * 64 + ((ks * 4 + lq) ^ (r & 7)) * 8];
            }
            #pragma unroll
            for (int ni = 0; ni < 4; ++ni) {
                int r = wn + ni * 16 + lr;
                bfr[ni] = *(const bf16x8*)&Bs[r * 64 + ((ks * 4 + lq) ^ (r & 7)) * 8];
            }
            #pragma unroll
            for (int mi = 0; mi < 4; ++mi)
                #pragma unroll
                for (int ni = 0; ni < 4; ++ni)
                    acc[mi][ni] = __builtin_amdgcn_mfma_f32_16x16x32_bf16(
                        af[mi], bfr[ni], acc[mi][ni], 0, 0, 0);
        }
        __syncthreads();
    }

    #pragma unroll
    for (int mi = 0; mi < 4; ++mi) {
        #pragma unroll
        for (int ni = 0; ni < 4; ++ni) {
            int n = n0 + wn + ni * 16 + lr;
            float bv = bias[n];
            #pragma unroll
            for (int r = 0; r < 4; ++r) {
                int m = m0 + wm + mi * 16 + lq * 4 + r;
                out[(size_t)m * CDIM + n] = acc[mi][ni][r] + bv;
            }
        }
    }
}

// ---------------------------------------------------------------- launch
extern "C" void kernel_launch(void* const* d_in, const int* in_sizes, int n_in,
                              void* d_out, int out_size, void* d_ws, size_t ws_size,
                              hipStream_t stream) {
    const float* x     = (const float*)d_in[0];
    const float* qkvw  = (const float*)d_in[1];
    const float* pos   = (const float*)d_in[2];
    const float* dwcw  = (const float*)d_in[3];
    const float* dwcb  = (const float*)d_in[4];
    const float* projw = (const float*)d_in[5];
    const float* projb = (const float*)d_in[6];
    float* out = (float*)d_out;

    char* ws = (char*)d_ws;
    size_t off = 0;
    auto alloc = [&](size_t bytes) -> void* {
        void* p = ws + off;
        off += (bytes + 255) & ~(size_t)255;
        return p;
    };
    bf16* qkvw_b = (bf16*)alloc((size_t)3 * CDIM * CDIM * 2);
    bf16* projw_b = (bf16*)alloc((size_t)CDIM * CDIM * 2);
    bf16* qh  = (bf16*)alloc((size_t)BHN * SEQ * HD * 2);
    bf16* khb = (bf16*)alloc((size_t)BHN * SEQ * HD * 2);   // reused as out_pre
    bf16* vh  = (bf16*)alloc((size_t)BHN * SEQ * HD * 2);
    float* kvb   = (float*)alloc((size_t)BHN * HD * HD * 4);
    float* ksumb = (float*)alloc((size_t)BHN * HD * 4);

    hipLaunchKernelGGL(convert_w, dim3(1024), dim3(256), 0, stream,
                       qkvw, projw, qkvw_b, projw_b, kvb, ksumb);
    hipLaunchKernelGGL(gemm_qkv, dim3(9, 512), dim3(256), 0, stream,
                       x, qkvw_b, pos, qh, khb, vh);
    hipLaunchKernelGGL(kv_reduce, dim3(8, BHN), dim3(256), 0, stream,
                       khb, vh, kvb, ksumb);
    bf16* outp = khb;   // kh is dead after kv_reduce; reuse as out_pre
    hipLaunchKernelGGL(attn_out, dim3(8, BHN), dim3(256), 0, stream,
                       qh, vh, kvb, ksumb, dwcw, dwcb, outp);
    hipLaunchKernelGGL(gemm_proj, dim3(3, 512), dim3(256), 0, stream,
                       outp, projw_b, projb, out);
}